// Round 5
// baseline (396.564 us; speedup 1.0000x reference)
//
#include <hip/hip_runtime.h>

// B=2, L=2048, DIM=1024, H=16, HD=64; scale folded into Q: 0.125*log2e; mask: -60*log2e
#define LL 2048
#define NHEADS 16
#define HDIM 64
#define QSCALE 0.18033688011112042f   // 0.125 * log2(e)
#define MASKC1 -86.56170245333780f    // -60 * log2(e)

typedef __attribute__((ext_vector_type(8))) __bf16 bf16x8;
typedef __attribute__((ext_vector_type(4))) float f32x4;
typedef __attribute__((ext_vector_type(4))) int i32x4;

__device__ __forceinline__ unsigned short f2bf(float f) {
  unsigned int u = __builtin_bit_cast(unsigned int, f);
  u += 0x7fffu + ((u >> 16) & 1u);   // RNE
  return (unsigned short)(u >> 16);
}

__device__ __forceinline__ bf16x8 ld_frag(const unsigned short* p) {
  return *reinterpret_cast<const bf16x8*>(p);
}

// async global->LDS, 16B per lane (used by qkv_gemm only)
__device__ __forceinline__ void async_cp16(const unsigned short* g, unsigned short* l) {
  __builtin_amdgcn_global_load_lds(
      (const __attribute__((address_space(1))) unsigned int*)(unsigned long long)(g),
      (__attribute__((address_space(3))) unsigned int*)(unsigned int)(unsigned long long)(l),
      16, 0, 0);
}

// ---------------- fused prep: x fp32->bf16 (blocks 0..4095) + W transpose (4096..4863) ----------
__global__ __launch_bounds__(256) void prep_kernel(
    const float* __restrict__ x, const float* __restrict__ Wq, const float* __restrict__ Wk,
    const float* __restrict__ Wv, unsigned short* __restrict__ xb,
    unsigned short* __restrict__ WtAll) {
  __shared__ float t[64][65];
  int blk = blockIdx.x;
  if (blk < 4096) {
    int i = (blk * 256 + threadIdx.x) * 4;
    float4 v = *reinterpret_cast<const float4*>(x + i);
    ushort4 o;
    o.x = f2bf(v.x); o.y = f2bf(v.y); o.z = f2bf(v.z); o.w = f2bf(v.w);
    *reinterpret_cast<ushort4*>(xb + i) = o;
  } else {
    int idx = blk - 4096;
    int z = idx >> 8; idx &= 255;
    const float* W = (z == 0) ? Wq : (z == 1) ? Wk : Wv;
    unsigned short* dst = WtAll + (size_t)z * 1024 * 1024;
    int n0 = (idx & 15) * 64, k0 = (idx >> 4) * 64;
    int tx = threadIdx.x & 63, ty = threadIdx.x >> 6;
#pragma unroll
    for (int p = 0; p < 16; ++p) {
      int kr = p * 4 + ty;
      t[kr][tx] = W[(size_t)(k0 + kr) * 1024 + n0 + tx];
    }
    __syncthreads();
#pragma unroll
    for (int p = 0; p < 16; ++p) {
      int nr = p * 4 + ty;
      dst[(size_t)(n0 + nr) * 1024 + k0 + tx] = f2bf(t[tx][nr]);
    }
  }
}

// ---------------- prep: em = bf16(exp2(mask*MASKC1)), tile-major [b][kb][q][pos], pos=4c+q ------
__global__ __launch_bounds__(256) void em_prep_kernel(const float* __restrict__ mask,
                                                      unsigned short* __restrict__ em) {
  unsigned int t = blockIdx.x * 256 + threadIdx.x;   // [0, 2^21)
  int c = t & 15;
  int q = (t >> 4) & 2047;
  int kb = (t >> 15) & 31;
  int b = t >> 20;
  const float* src = mask + ((size_t)b * LL + q) * LL + kb * 64 + c;
  ushort4 o;
  o.x = f2bf(__builtin_amdgcn_exp2f(src[0]  * MASKC1));
  o.y = f2bf(__builtin_amdgcn_exp2f(src[16] * MASKC1));
  o.z = f2bf(__builtin_amdgcn_exp2f(src[32] * MASKC1));
  o.w = f2bf(__builtin_amdgcn_exp2f(src[48] * MASKC1));
  *reinterpret_cast<ushort4*>(em + (((size_t)b * 32 + kb) * LL + q) * 64 + 4 * c) = o;
}

// ---------------- QKV projection GEMM (async staging, swizzled rows) ----------------
// grid (8, 32, 3). z==0: Q bf16 [bh][l][d] * QSCALE; z==1: K [bh][l][d];
// z==2: V^T tile-major [bh][tile=l/64][d][pos], pos=4c+q permuted within tile.
__global__ __launch_bounds__(256) void qkv_gemm_kernel(
    const unsigned short* __restrict__ xb, const unsigned short* __restrict__ WtAll,
    const float* __restrict__ bq, const float* __restrict__ bk, const float* __restrict__ bv,
    unsigned short* __restrict__ qkv) {
  const int z = blockIdx.z;
  const unsigned short* Wt = WtAll + (size_t)z * 1024 * 1024;
  const float* bias = (z == 0) ? bq : (z == 1) ? bk : bv;
  unsigned short* outb = qkv + (size_t)z * 4194304;

  __shared__ __align__(16) unsigned short smem[16384];
  unsigned short* As = smem;
  unsigned short* Bs = smem + 8192;

  const int tid = threadIdx.x;
  const int w = tid >> 6, lane = tid & 63, g = lane >> 4, cc = lane & 15;
  const int wm = w >> 1, wn = w & 1;
  const int m0 = blockIdx.y * 128, n0 = blockIdx.x * 128;
  const int srow = lane >> 3;
  const int gc = ((lane & 7) - srow) & 7;
  const unsigned short* ga = xb + (size_t)(m0 + w * 32 + srow) * 1024 + gc * 8;
  const unsigned short* gb = Wt + (size_t)(n0 + w * 32 + srow) * 1024 + gc * 8;
  unsigned short* la = As + w * 2048;
  unsigned short* lb = Bs + w * 2048;

  f32x4 acc[4][4];
#pragma unroll
  for (int i = 0; i < 4; ++i)
#pragma unroll
    for (int j = 0; j < 4; ++j) acc[i][j] = (f32x4)0.0f;

  for (int kk = 0; kk < 1024; kk += 64) {
    __syncthreads();
#pragma unroll
    for (int i = 0; i < 4; ++i) {
      async_cp16(ga + i * 8192 + kk, la + i * 512);
      async_cp16(gb + i * 8192 + kk, lb + i * 512);
    }
    __syncthreads();
    bf16x8 af[4][2], bfr[4][2];
#pragma unroll
    for (int mt = 0; mt < 4; ++mt)
#pragma unroll
      for (int ks = 0; ks < 2; ++ks)
        af[mt][ks] = ld_frag(&As[(wm * 64 + mt * 16 + cc) * 64 + ((4 * ks + g + cc) & 7) * 8]);
#pragma unroll
    for (int nt = 0; nt < 4; ++nt)
#pragma unroll
      for (int ks = 0; ks < 2; ++ks)
        bfr[nt][ks] = ld_frag(&Bs[(wn * 64 + nt * 16 + cc) * 64 + ((4 * ks + g + cc) & 7) * 8]);
#pragma unroll
    for (int mt = 0; mt < 4; ++mt)
#pragma unroll
      for (int nt = 0; nt < 4; ++nt)
#pragma unroll
        for (int ks = 0; ks < 2; ++ks)
          acc[mt][nt] = __builtin_amdgcn_mfma_f32_16x16x32_bf16(af[mt][ks], bfr[nt][ks],
                                                                acc[mt][nt], 0, 0, 0);
  }

  if (z != 2) {
    const float sc = (z == 0) ? QSCALE : 1.0f;
#pragma unroll
    for (int nt = 0; nt < 4; ++nt) {
      int n = n0 + wn * 64 + nt * 16 + cc;
      float bval = bias[n];
      int h = n >> 6, d = n & 63;
#pragma unroll
      for (int mt = 0; mt < 4; ++mt) {
#pragma unroll
        for (int r = 0; r < 4; ++r) {
          int m = m0 + wm * 64 + mt * 16 + g * 4 + r;
          int b = m >> 11, l = m & 2047;
          outb[(((size_t)(b * NHEADS + h) * LL) + l) * HDIM + d] =
              f2bf((acc[mt][nt][r] + bval) * sc);
        }
      }
    }
  } else {
    // V^T tile-major epilogue; key permutation within 64-tile: local mt*16+g*4+r -> pos 16g+4r+mt
    __syncthreads();
#pragma unroll
    for (int nt = 0; nt < 4; ++nt) {
      int nr = wn * 64 + nt * 16 + cc;
      float bval = bias[n0 + nr];
#pragma unroll
      for (int mt = 0; mt < 4; ++mt)
#pragma unroll
        for (int r = 0; r < 4; ++r)
          smem[nr * 128 + wm * 64 + 16 * g + 4 * r + mt] = f2bf(acc[mt][nt][r] + bval);
    }
    __syncthreads();
    int row = tid >> 1, half = tid & 1;
    int n = n0 + row, hh = n >> 6, dd = n & 63;
    int bb = m0 >> 11;
    int tI = ((m0 & 2047) >> 6) + half;
    unsigned short* dst =
        outb + (size_t)(bb * NHEADS + hh) * (LL * HDIM) + (size_t)tI * 4096 + dd * 64;
#pragma unroll
    for (int i = 0; i < 8; ++i)
      *reinterpret_cast<uint4*>(dst + i * 8) =
          *reinterpret_cast<const uint4*>(&smem[row * 128 + half * 64 + i * 8]);
  }
}

// ---------------- flash attention: barrier-free, LDS-minimal ----------------
// grid (32, 32), 256 thr = 4 independent waves; wave w owns q rows [q0+w*16, +16).
// K/V fragments read directly from global (L2), K & em software-pipelined one kt ahead.
// Only P round-trips through wave-private LDS. li via ones-vector MFMA (no shuffles).
__global__ __launch_bounds__(256, 3) void flash_kernel(
    const unsigned short* __restrict__ Qb, const unsigned short* __restrict__ Kb,
    const unsigned short* __restrict__ Vt, const unsigned short* __restrict__ Em,
    float* __restrict__ out) {
  const int bh = blockIdx.y, b = bh >> 4, h = bh & 15;
  const int q0 = blockIdx.x * 64;
  const int tid = threadIdx.x, w = tid >> 6, lane = tid & 63, g = lane >> 4, cc = lane & 15;
  const size_t bhoff = (size_t)bh * (LL * HDIM);

  __shared__ __align__(16) unsigned short Ps[4][16 * 64];  // 2KB per wave, wave-private
  unsigned short* myP = Ps[w];

  // A-frag of Q (loop-invariant): rows q0+w*16+cc
  const unsigned short* qp = Qb + bhoff + (size_t)(q0 + w * 16 + cc) * HDIM + g * 8;
  bf16x8 aq0 = ld_frag(qp);
  bf16x8 aq1 = ld_frag(qp + 32);

  // global fragment pointers (imm offsets: nt*2048B + ks*64B within 13-bit range)
  const unsigned short* kpA = Kb + bhoff + cc * 64 + g * 8;   // K rows nt*16+cc, d-chunk g
  const unsigned short* kpB = kpA + 2048;                     // nt = 2,3
  const unsigned short* vpA = Vt + bhoff + cc * 64 + g * 8;   // V^T tile: d rows nt*16+cc
  const unsigned short* vpB = vpA + 2048;
  const unsigned short* ep =
      Em + ((size_t)b * 65536 + (q0 + w * 16 + g * 4)) * 64 + 4 * cc;

  // build ones B-frag (bf16 1.0 = 0x3F80)
  i32x4 onesi = {0x3F803F80, 0x3F803F80, 0x3F803F80, 0x3F803F80};
  bf16x8 vones = __builtin_bit_cast(bf16x8, onesi);

  f32x4 oacc[4], liacc;
#pragma unroll
  for (int nt = 0; nt < 4; ++nt) oacc[nt] = (f32x4)0.0f;
  liacc = (f32x4)0.0f;

  // preload kt=0: K frags + em
  bf16x8 bk[4][2];
  bk[0][0] = ld_frag(kpA);        bk[0][1] = ld_frag(kpA + 32);
  bk[1][0] = ld_frag(kpA + 1024); bk[1][1] = ld_frag(kpA + 1056);
  bk[2][0] = ld_frag(kpB);        bk[2][1] = ld_frag(kpB + 32);
  bk[3][0] = ld_frag(kpB + 1024); bk[3][1] = ld_frag(kpB + 1056);
  uint2 emv[4];
#pragma unroll
  for (int r = 0; r < 4; ++r)
    emv[r] = *reinterpret_cast<const uint2*>(ep + r * 64);

  for (int kt = 0; kt < 32; ++kt) {
    // S = Q @ K^T (waits on bk loaded last iteration -> latency hidden)
    f32x4 sacc[4];
#pragma unroll
    for (int nt = 0; nt < 4; ++nt) sacc[nt] = (f32x4)0.0f;
#pragma unroll
    for (int nt = 0; nt < 4; ++nt) {
      sacc[nt] = __builtin_amdgcn_mfma_f32_16x16x32_bf16(aq0, bk[nt][0], sacc[nt], 0, 0, 0);
      sacc[nt] = __builtin_amdgcn_mfma_f32_16x16x32_bf16(aq1, bk[nt][1], sacc[nt], 0, 0, 0);
    }

    // issue V frag loads for THIS kt (softmax below covers part of the latency)
    bf16x8 bv[4][2];
    bv[0][0] = ld_frag(vpA);        bv[0][1] = ld_frag(vpA + 32);
    bv[1][0] = ld_frag(vpA + 1024); bv[1][1] = ld_frag(vpA + 1056);
    bv[2][0] = ld_frag(vpB);        bv[2][1] = ld_frag(vpB + 32);
    bv[3][0] = ld_frag(vpB + 1024); bv[3][1] = ld_frag(vpB + 1056);

    // softmax: p = exp2(s) * em (em from last-iteration load); pack -> wave-private LDS
#pragma unroll
    for (int r = 0; r < 4; ++r) {
      unsigned int ex = emv[r].x, ey = emv[r].y;
      float e0 = __builtin_bit_cast(float, ex << 16);
      float e1 = __builtin_bit_cast(float, ex & 0xffff0000u);
      float e2 = __builtin_bit_cast(float, ey << 16);
      float e3 = __builtin_bit_cast(float, ey & 0xffff0000u);
      float p0 = __builtin_amdgcn_exp2f(sacc[0][r]) * e0;
      float p1 = __builtin_amdgcn_exp2f(sacc[1][r]) * e1;
      float p2 = __builtin_amdgcn_exp2f(sacc[2][r]) * e2;
      float p3 = __builtin_amdgcn_exp2f(sacc[3][r]) * e3;
      unsigned int u01 = __builtin_amdgcn_perm(__builtin_bit_cast(unsigned int, p1),
                                               __builtin_bit_cast(unsigned int, p0),
                                               0x07060302u);
      unsigned int u23 = __builtin_amdgcn_perm(__builtin_bit_cast(unsigned int, p3),
                                               __builtin_bit_cast(unsigned int, p2),
                                               0x07060302u);
      uint2 pk; pk.x = u01; pk.y = u23;
      int prow = g * 4 + r;
      *reinterpret_cast<uint2*>(
          &myP[prow * 64 + ((((cc >> 1) + prow) & 7) << 3) + ((cc & 1) << 2)]) = pk;
    }

    // advance pointers (guarded: last iteration re-reads kt=31 harmlessly, stays in-bounds)
    const int adv = (kt < 31) ? 1 : 0;
    kpA += adv * 4096; kpB += adv * 4096;
    vpA += adv * 4096; vpB += adv * 4096;
    ep += (size_t)adv * 131072;

    // prefetch K frags + em for kt+1
    bk[0][0] = ld_frag(kpA);        bk[0][1] = ld_frag(kpA + 32);
    bk[1][0] = ld_frag(kpA + 1024); bk[1][1] = ld_frag(kpA + 1056);
    bk[2][0] = ld_frag(kpB);        bk[2][1] = ld_frag(kpB + 32);
    bk[3][0] = ld_frag(kpB + 1024); bk[3][1] = ld_frag(kpB + 1056);
#pragma unroll
    for (int r = 0; r < 4; ++r)
      emv[r] = *reinterpret_cast<const uint2*>(ep + r * 64);

    asm volatile("" ::: "memory");  // P stores ordered before same-wave P frag reads

    // A-frag of P (rows cc of this wave's 16)
    bf16x8 ap0 = ld_frag(&myP[cc * 64 + (((g + cc) & 7) << 3)]);
    bf16x8 ap1 = ld_frag(&myP[cc * 64 + (((4 + g + cc) & 7) << 3)]);

    // O += P @ V ; li += P @ ones (exact consistency: sums the same bf16 P values)
#pragma unroll
    for (int nt = 0; nt < 4; ++nt) {
      oacc[nt] = __builtin_amdgcn_mfma_f32_16x16x32_bf16(ap0, bv[nt][0], oacc[nt], 0, 0, 0);
      oacc[nt] = __builtin_amdgcn_mfma_f32_16x16x32_bf16(ap1, bv[nt][1], oacc[nt], 0, 0, 0);
    }
    liacc = __builtin_amdgcn_mfma_f32_16x16x32_bf16(ap0, vones, liacc, 0, 0, 0);
    liacc = __builtin_amdgcn_mfma_f32_16x16x32_bf16(ap1, vones, liacc, 0, 0, 0);
  }

  // epilogue: liacc[r] already the full row-sum in every lane (ones-MFMA) -> no shuffles
#pragma unroll
  for (int r = 0; r < 4; ++r) {
    float inv = 1.0f / liacc[r];
    int qrow = q0 + w * 16 + g * 4 + r;
#pragma unroll
    for (int nt = 0; nt < 4; ++nt)
      out[((size_t)b * LL + qrow) * 1024 + h * 64 + nt * 16 + cc] = oacc[nt][r] * inv;
  }
}

extern "C" void kernel_launch(void* const* d_in, const int* in_sizes, int n_in,
                              void* d_out, int out_size, void* d_ws, size_t ws_size,
                              hipStream_t stream) {
  const float* x    = (const float*)d_in[0];
  const float* mask = (const float*)d_in[1];
  const float* Wq   = (const float*)d_in[2];
  const float* bq   = (const float*)d_in[3];
  const float* Wk   = (const float*)d_in[4];
  const float* bk   = (const float*)d_in[5];
  const float* Wv   = (const float*)d_in[6];
  const float* bv   = (const float*)d_in[7];
  float* out = (float*)d_out;
  (void)in_sizes; (void)n_in; (void)out_size; (void)ws_size;

  char* ws = (char*)d_ws;
  // qkv @0 (24 MiB); xb @24 (8 MiB); Wt @32 (6 MiB);
  // em @24 (16 MiB) overlaps xb/Wt — dead after qkv_gemm; em_prep MUST launch after qkv_gemm.
  unsigned short* qkv = (unsigned short*)(ws);
  unsigned short* xb  = (unsigned short*)(ws + (24u << 20));
  unsigned short* Wt  = (unsigned short*)(ws + (32u << 20));
  unsigned short* em  = (unsigned short*)(ws + (24u << 20));

  prep_kernel<<<dim3(4864), dim3(256), 0, stream>>>(x, Wq, Wk, Wv, xb, Wt);
  qkv_gemm_kernel<<<dim3(8, 32, 3), dim3(256), 0, stream>>>(xb, Wt, bq, bk, bv, qkv);
  em_prep_kernel<<<dim3(8192), dim3(256), 0, stream>>>(mask, em);
  flash_kernel<<<dim3(32, 32), dim3(256), 0, stream>>>(qkv, qkv + 4194304, qkv + 8388608,
                                                       em, out);
}

// Round 6
// 218.252 us; speedup vs baseline: 1.8170x; 1.8170x over previous
//
#include <hip/hip_runtime.h>

// B=2, L=2048, DIM=1024, H=16, HD=64; scale folded into Q: 0.125*log2e; mask: -60*log2e
#define LL 2048
#define NHEADS 16
#define HDIM 64
#define QSCALE 0.18033688011112042f   // 0.125 * log2(e)
#define MASKC1 -86.56170245333780f    // -60 * log2(e)

typedef __attribute__((ext_vector_type(8))) __bf16 bf16x8;
typedef __attribute__((ext_vector_type(4))) float f32x4;
typedef __attribute__((ext_vector_type(16))) float f32x16;
typedef __attribute__((ext_vector_type(4))) int i32x4;

__device__ __forceinline__ unsigned short f2bf(float f) {
  unsigned int u = __builtin_bit_cast(unsigned int, f);
  u += 0x7fffu + ((u >> 16) & 1u);   // RNE
  return (unsigned short)(u >> 16);
}

__device__ __forceinline__ bf16x8 ld_frag(const unsigned short* p) {
  return *reinterpret_cast<const bf16x8*>(p);
}

// async global->LDS, 16B per lane; LDS dest = wave-uniform base + lane*16
__device__ __forceinline__ void async_cp16(const unsigned short* g, unsigned short* l) {
  __builtin_amdgcn_global_load_lds(
      (const __attribute__((address_space(1))) unsigned int*)(unsigned long long)(g),
      (__attribute__((address_space(3))) unsigned int*)(unsigned int)(unsigned long long)(l),
      16, 0, 0);
}

// ---------------- fused prep: x fp32->bf16 (blocks 0..4095) + W transpose (4096..4863) ----------
__global__ __launch_bounds__(256) void prep_kernel(
    const float* __restrict__ x, const float* __restrict__ Wq, const float* __restrict__ Wk,
    const float* __restrict__ Wv, unsigned short* __restrict__ xb,
    unsigned short* __restrict__ WtAll) {
  __shared__ float t[64][65];
  int blk = blockIdx.x;
  if (blk < 4096) {
    int i = (blk * 256 + threadIdx.x) * 4;
    float4 v = *reinterpret_cast<const float4*>(x + i);
    ushort4 o;
    o.x = f2bf(v.x); o.y = f2bf(v.y); o.z = f2bf(v.z); o.w = f2bf(v.w);
    *reinterpret_cast<ushort4*>(xb + i) = o;
  } else {
    int idx = blk - 4096;
    int z = idx >> 8; idx &= 255;
    const float* W = (z == 0) ? Wq : (z == 1) ? Wk : Wv;
    unsigned short* dst = WtAll + (size_t)z * 1024 * 1024;
    int n0 = (idx & 15) * 64, k0 = (idx >> 4) * 64;
    int tx = threadIdx.x & 63, ty = threadIdx.x >> 6;
#pragma unroll
    for (int p = 0; p < 16; ++p) {
      int kr = p * 4 + ty;
      t[kr][tx] = W[(size_t)(k0 + kr) * 1024 + n0 + tx];
    }
    __syncthreads();
#pragma unroll
    for (int p = 0; p < 16; ++p) {
      int nr = p * 4 + ty;
      dst[(size_t)(n0 + nr) * 1024 + k0 + tx] = f2bf(t[tx][nr]);
    }
  }
}

// ---------------- prep: em tile-major [b][kb][q][pos64], pos = 2c + t  (key = t*32 + c) --------
__global__ __launch_bounds__(256) void em_prep_kernel(const float* __restrict__ mask,
                                                      unsigned short* __restrict__ em) {
  unsigned int t = blockIdx.x * 256 + threadIdx.x;   // [0, 2^21)
  int p = t & 15;
  int q = (t >> 4) & 2047;
  int kb = (t >> 15) & 31;
  int b = t >> 20;
  const float* src = mask + ((size_t)b * LL + q) * LL + kb * 64;
  ushort4 o;
  o.x = f2bf(__builtin_amdgcn_exp2f(src[2 * p]      * MASKC1));  // pos 4p   -> key 2p
  o.y = f2bf(__builtin_amdgcn_exp2f(src[32 + 2 * p] * MASKC1));  // pos 4p+1 -> key 32+2p
  o.z = f2bf(__builtin_amdgcn_exp2f(src[2 * p + 1]  * MASKC1));  // pos 4p+2 -> key 2p+1
  o.w = f2bf(__builtin_amdgcn_exp2f(src[33 + 2 * p] * MASKC1));  // pos 4p+3 -> key 33+2p
  *reinterpret_cast<ushort4*>(em + (((size_t)b * 32 + kb) * LL + q) * 64 + 4 * p) = o;
}

// ---------------- QKV projection GEMM (async staging, swizzled rows) ----------------
// grid (8, 32, 3). z==0: Q bf16 [bh][l][d] * QSCALE; z==1: K [bh][l][d];
// z==2: V^T tile-major [bh][tile=l/64][d][pos64], pos = 2*(k64&31) + (k64>>5).
__global__ __launch_bounds__(256) void qkv_gemm_kernel(
    const unsigned short* __restrict__ xb, const unsigned short* __restrict__ WtAll,
    const float* __restrict__ bq, const float* __restrict__ bk, const float* __restrict__ bv,
    unsigned short* __restrict__ qkv) {
  const int z = blockIdx.z;
  const unsigned short* Wt = WtAll + (size_t)z * 1024 * 1024;
  const float* bias = (z == 0) ? bq : (z == 1) ? bk : bv;
  unsigned short* outb = qkv + (size_t)z * 4194304;

  __shared__ __align__(16) unsigned short smem[16384];
  unsigned short* As = smem;
  unsigned short* Bs = smem + 8192;

  const int tid = threadIdx.x;
  const int w = tid >> 6, lane = tid & 63, g = lane >> 4, cc = lane & 15;
  const int wm = w >> 1, wn = w & 1;
  const int m0 = blockIdx.y * 128, n0 = blockIdx.x * 128;
  const int srow = lane >> 3;
  const int gc = ((lane & 7) - srow) & 7;
  const unsigned short* ga = xb + (size_t)(m0 + w * 32 + srow) * 1024 + gc * 8;
  const unsigned short* gb = Wt + (size_t)(n0 + w * 32 + srow) * 1024 + gc * 8;
  unsigned short* la = As + w * 2048;
  unsigned short* lb = Bs + w * 2048;

  f32x4 acc[4][4];
#pragma unroll
  for (int i = 0; i < 4; ++i)
#pragma unroll
    for (int j = 0; j < 4; ++j) acc[i][j] = (f32x4)0.0f;

  for (int kk = 0; kk < 1024; kk += 64) {
    __syncthreads();
#pragma unroll
    for (int i = 0; i < 4; ++i) {
      async_cp16(ga + i * 8192 + kk, la + i * 512);
      async_cp16(gb + i * 8192 + kk, lb + i * 512);
    }
    __syncthreads();
    bf16x8 af[4][2], bfr[4][2];
#pragma unroll
    for (int mt = 0; mt < 4; ++mt)
#pragma unroll
      for (int ks = 0; ks < 2; ++ks)
        af[mt][ks] = ld_frag(&As[(wm * 64 + mt * 16 + cc) * 64 + ((4 * ks + g + cc) & 7) * 8]);
#pragma unroll
    for (int nt = 0; nt < 4; ++nt)
#pragma unroll
      for (int ks = 0; ks < 2; ++ks)
        bfr[nt][ks] = ld_frag(&Bs[(wn * 64 + nt * 16 + cc) * 64 + ((4 * ks + g + cc) & 7) * 8]);
#pragma unroll
    for (int mt = 0; mt < 4; ++mt)
#pragma unroll
      for (int nt = 0; nt < 4; ++nt)
#pragma unroll
        for (int ks = 0; ks < 2; ++ks)
          acc[mt][nt] = __builtin_amdgcn_mfma_f32_16x16x32_bf16(af[mt][ks], bfr[nt][ks],
                                                                acc[mt][nt], 0, 0, 0);
  }

  if (z != 2) {
    const float sc = (z == 0) ? QSCALE : 1.0f;
#pragma unroll
    for (int nt = 0; nt < 4; ++nt) {
      int n = n0 + wn * 64 + nt * 16 + cc;
      float bval = bias[n];
      int h = n >> 6, d = n & 63;
#pragma unroll
      for (int mt = 0; mt < 4; ++mt) {
#pragma unroll
        for (int r = 0; r < 4; ++r) {
          int m = m0 + wm * 64 + mt * 16 + g * 4 + r;
          int b = m >> 11, l = m & 2047;
          outb[(((size_t)(b * NHEADS + h) * LL) + l) * HDIM + d] =
              f2bf((acc[mt][nt][r] + bval) * sc);
        }
      }
    }
  } else {
    // V^T tile-major; key k64 = mt*16+g*4+r within the 64-half -> pos = 2*(k64&31)+(k64>>5)
    //   = 32*(mt&1) + 8g + 2r + (mt>>1)
    __syncthreads();
#pragma unroll
    for (int nt = 0; nt < 4; ++nt) {
      int nr = wn * 64 + nt * 16 + cc;
      float bval = bias[n0 + nr];
#pragma unroll
      for (int mt = 0; mt < 4; ++mt)
#pragma unroll
        for (int r = 0; r < 4; ++r)
          smem[nr * 128 + wm * 64 + 32 * (mt & 1) + 8 * g + 2 * r + (mt >> 1)] =
              f2bf(acc[mt][nt][r] + bval);
    }
    __syncthreads();
    int row = tid >> 1, half = tid & 1;
    int n = n0 + row, hh = n >> 6, dd = n & 63;
    int bb = m0 >> 11;
    int tI = ((m0 & 2047) >> 6) + half;
    unsigned short* dst =
        outb + (size_t)(bb * NHEADS + hh) * (LL * HDIM) + (size_t)tI * 4096 + dd * 64;
#pragma unroll
    for (int i = 0; i < 8; ++i)
      *reinterpret_cast<uint4*>(dst + i * 8) =
          *reinterpret_cast<const uint4*>(&smem[row * 128 + half * 64 + i * 8]);
  }
}

// ---------------- flash attention: 32x32x16 MFMA core ----------------
// grid (32, 32): 64-row q-tiles, 128 threads = 2 waves, wave w owns rows [q0+w*32,+32).
// LDS 40KB -> 4 blocks/CU. Staged K/V ping-pong (1 barrier/kt); P via b32 pair-pack;
// li via ones-MFMA. C/D: col=lane&31, row=(reg&3)+8(reg>>2)+4(lane>>5); A/B: k=8*(lane>>5)+j.
__global__ __launch_bounds__(128, 2) void flash_kernel(
    const unsigned short* __restrict__ Qb, const unsigned short* __restrict__ Kb,
    const unsigned short* __restrict__ Vt, const unsigned short* __restrict__ Em,
    float* __restrict__ out) {
  const int bh = blockIdx.y, b = bh >> 4, h = bh & 15;
  const int q0 = blockIdx.x * 64;
  const int tid = threadIdx.x, w = tid >> 6, lane = tid & 63;
  const int cl = lane & 31, hf = lane >> 5;
  const size_t bhoff = (size_t)bh * (LL * HDIM);

  __shared__ __align__(16) unsigned short Ks[2][64 * 64];  // [key][d] swizzled
  __shared__ __align__(16) unsigned short Vs[2][64 * 64];  // [d][pos] swizzled
  __shared__ __align__(16) unsigned short Ps[2][32 * 64];  // per-wave P, swizzled
  unsigned short* myP = Ps[w];

  // Q A-frags (loop-invariant): row = q0+w*32+cl, k = ks*16 + hf*8 + j
  bf16x8 aq[4];
  {
    const unsigned short* qp = Qb + bhoff + (size_t)(q0 + w * 32 + cl) * HDIM + hf * 8;
#pragma unroll
    for (int ks = 0; ks < 4; ++ks) aq[ks] = ld_frag(qp + ks * 16);
  }

  // staging: wave w stages K rows [w*32,+32) and V d-rows [w*32,+32), 4 asyncs each
  const int srow = lane >> 3;
  const int gcs = ((lane & 7) - srow) & 7;
  const unsigned short* kgp = Kb + bhoff + (size_t)(w * 32 + srow) * 64 + gcs * 8;
  const unsigned short* vgp = Vt + bhoff + (size_t)(w * 32 + srow) * 64 + gcs * 8;

  i32x4 onesi = {0x3F803F80, 0x3F803F80, 0x3F803F80, 0x3F803F80};
  bf16x8 vones = __builtin_bit_cast(bf16x8, onesi);

  f32x16 oacc0 = (f32x16)0.0f, oacc1 = (f32x16)0.0f, liacc = (f32x16)0.0f;

  // em base: row q0+w*32+4*hf, col-pair offset 2*cl shorts; per-reg row offset R0(r)*64
  const unsigned short* ebase =
      Em + (((size_t)b * 32) * LL + (q0 + w * 32 + 4 * hf)) * 64 + 2 * cl;

  // prologue: stage tile 0, load em(0)
#pragma unroll
  for (int i = 0; i < 4; ++i) {
    async_cp16(kgp + i * 512, Ks[0] + w * 2048 + i * 512);
    async_cp16(vgp + i * 512, Vs[0] + w * 2048 + i * 512);
  }
  unsigned int emv[16];
#pragma unroll
  for (int r = 0; r < 16; ++r)
    emv[r] = *reinterpret_cast<const unsigned int*>(
        ebase + (size_t)((r & 3) + 8 * (r >> 2)) * 64);

#pragma unroll 2
  for (int kt = 0; kt < 32; ++kt) {
    const int buf = kt & 1;
    __syncthreads();  // drains own asyncs -> tile kt ready; prior reads of buf^1 done
    if (kt + 1 < 32) {
      const int nb = buf ^ 1;
      const unsigned short* ksrc = kgp + (size_t)(kt + 1) * 4096;
      const unsigned short* vsrc = vgp + (size_t)(kt + 1) * 4096;
#pragma unroll
      for (int i = 0; i < 4; ++i) {
        async_cp16(ksrc + i * 512, Ks[nb] + w * 2048 + i * 512);
        async_cp16(vsrc + i * 512, Vs[nb] + w * 2048 + i * 512);
      }
    }
    // prefetch em for kt+1
    const int ktn = (kt + 1 < 32) ? kt + 1 : 31;
    unsigned int emn[16];
#pragma unroll
    for (int r = 0; r < 16; ++r)
      emn[r] = *reinterpret_cast<const unsigned int*>(
          ebase + (size_t)ktn * 131072 + (size_t)((r & 3) + 8 * (r >> 2)) * 64);

    // S = Q @ K^T : two 32-key tiles
    bf16x8 bk[2][4];
#pragma unroll
    for (int t = 0; t < 2; ++t)
#pragma unroll
      for (int ks = 0; ks < 4; ++ks) {
        int row = t * 32 + cl;
        bk[t][ks] = ld_frag(&Ks[buf][row * 64 + (((2 * ks + hf + row) & 7) << 3)]);
      }
    f32x16 s0 = (f32x16)0.0f, s1 = (f32x16)0.0f;
#pragma unroll
    for (int ks = 0; ks < 4; ++ks) {
      s0 = __builtin_amdgcn_mfma_f32_32x32x16_bf16(aq[ks], bk[0][ks], s0, 0, 0, 0);
      s1 = __builtin_amdgcn_mfma_f32_32x32x16_bf16(aq[ks], bk[1][ks], s1, 0, 0, 0);
    }

    // softmax: p = exp2(s) * em; pack (p0,p1) -> b32 at [R][pos=2*cl]
#pragma unroll
    for (int r = 0; r < 16; ++r) {
      unsigned int eu = emv[r];
      float e0 = __builtin_bit_cast(float, eu << 16);
      float e1 = __builtin_bit_cast(float, eu & 0xffff0000u);
      float p0 = __builtin_amdgcn_exp2f(s0[r]) * e0;
      float p1 = __builtin_amdgcn_exp2f(s1[r]) * e1;
      unsigned int u = __builtin_amdgcn_perm(__builtin_bit_cast(unsigned int, p1),
                                             __builtin_bit_cast(unsigned int, p0),
                                             0x07060302u);
      int R = (r & 3) + 8 * (r >> 2) + 4 * hf;
      *reinterpret_cast<unsigned int*>(
          &myP[R * 64 + ((((cl >> 2) + R) & 7) << 3) + 2 * (cl & 3)]) = u;
    }
    asm volatile("" ::: "memory");  // P stores ordered before same-wave P frag reads

    // O += P @ V ; li += P @ ones
    bf16x8 ap[4];
#pragma unroll
    for (int ks = 0; ks < 4; ++ks)
      ap[ks] = ld_frag(&myP[cl * 64 + (((2 * ks + hf + cl) & 7) << 3)]);
    bf16x8 bv[2][4];
#pragma unroll
    for (int t = 0; t < 2; ++t)
#pragma unroll
      for (int ks = 0; ks < 4; ++ks) {
        int row = t * 32 + cl;
        bv[t][ks] = ld_frag(&Vs[buf][row * 64 + (((2 * ks + hf + row) & 7) << 3)]);
      }
#pragma unroll
    for (int ks = 0; ks < 4; ++ks) {
      oacc0 = __builtin_amdgcn_mfma_f32_32x32x16_bf16(ap[ks], bv[0][ks], oacc0, 0, 0, 0);
      oacc1 = __builtin_amdgcn_mfma_f32_32x32x16_bf16(ap[ks], bv[1][ks], oacc1, 0, 0, 0);
      liacc = __builtin_amdgcn_mfma_f32_32x32x16_bf16(ap[ks], vones, liacc, 0, 0, 0);
    }
#pragma unroll
    for (int r = 0; r < 16; ++r) emv[r] = emn[r];
  }

  // epilogue: liacc[r] = row-sum in every lane; normalize, write [B,L,H*HD] fp32
#pragma unroll
  for (int r = 0; r < 16; ++r) {
    float inv = 1.0f / liacc[r];
    int q = q0 + w * 32 + (r & 3) + 8 * (r >> 2) + 4 * hf;
    float* op = out + ((size_t)b * LL + q) * 1024 + h * 64 + cl;
    op[0]  = oacc0[r] * inv;
    op[32] = oacc1[r] * inv;
  }
}

extern "C" void kernel_launch(void* const* d_in, const int* in_sizes, int n_in,
                              void* d_out, int out_size, void* d_ws, size_t ws_size,
                              hipStream_t stream) {
  const float* x    = (const float*)d_in[0];
  const float* mask = (const float*)d_in[1];
  const float* Wq   = (const float*)d_in[2];
  const float* bq   = (const float*)d_in[3];
  const float* Wk   = (const float*)d_in[4];
  const float* bk   = (const float*)d_in[5];
  const float* Wv   = (const float*)d_in[6];
  const float* bv   = (const float*)d_in[7];
  float* out = (float*)d_out;
  (void)in_sizes; (void)n_in; (void)out_size; (void)ws_size;

  char* ws = (char*)d_ws;
  // qkv @0 (24 MiB); xb @24 (8 MiB); Wt @32 (6 MiB);
  // em @24 (16 MiB) overlaps xb/Wt — dead after qkv_gemm; em_prep MUST launch after qkv_gemm.
  unsigned short* qkv = (unsigned short*)(ws);
  unsigned short* xb  = (unsigned short*)(ws + (24u << 20));
  unsigned short* Wt  = (unsigned short*)(ws + (32u << 20));
  unsigned short* em  = (unsigned short*)(ws + (24u << 20));

  prep_kernel<<<dim3(4864), dim3(256), 0, stream>>>(x, Wq, Wk, Wv, xb, Wt);
  qkv_gemm_kernel<<<dim3(8, 32, 3), dim3(256), 0, stream>>>(xb, Wt, bq, bk, bv, qkv);
  em_prep_kernel<<<dim3(8192), dim3(256), 0, stream>>>(mask, em);
  flash_kernel<<<dim3(32, 32), dim3(128), 0, stream>>>(qkv, qkv + 4194304, qkv + 8388608,
                                                       em, out);
}